// Round 4
// baseline (3455.174 us; speedup 1.0000x reference)
//
#include <hip/hip_runtime.h>

typedef short short8 __attribute__((ext_vector_type(8)));
typedef float f32x16 __attribute__((ext_vector_type(16)));

#define AS1 __attribute__((address_space(1)))
#define AS3 __attribute__((address_space(3)))

// ---- workspace layout (bytes) ----
static constexpr size_t XP_OFF = 0;            // xp bf16 [T=512][G=32][B=64][Q=64]  134217728
static constexpr size_t HS_OFF = 134217728;    // hs bf16 [B*T=32768][H=512]          33554432
static constexpr size_t U_OFF  = 167772160;    // U  bf16 [P=2048][K=512]              2097152
static constexpr size_t WX_OFF = 169869312;    // WxT bf16 [P=2048][K=256]             1048576
static constexpr size_t WY_OFF = 170917888;    // WyT bf16 [N=256][K=512]               262144
static constexpr size_t BI_OFF = 171180032;    // bias fp32 [2048] (permuted)             8192
static constexpr size_t HB_OFF = 171188224;    // h ping-pong bf16 2 x [64][512]         131072
static constexpr size_t FL_OFF = 171319296;    // flags [32] x 64B                        2048

static __device__ __forceinline__ unsigned short f2bf(float f) {
  unsigned u = __float_as_uint(f);
  unsigned r = (u + 0x7fffu + ((u >> 16) & 1u)) >> 16;
  return (unsigned short)r;
}
static __device__ __forceinline__ float bf2f(unsigned short s) {
  return __uint_as_float(((unsigned)s) << 16);
}
static __device__ __forceinline__ float sigf(float x) { return 1.0f / (1.0f + __expf(-x)); }
static __device__ __forceinline__ float tanhf_(float x) { return 1.0f - 2.0f / (1.0f + __expf(2.0f * x)); }

static __device__ __forceinline__ void gld_lds16(const void* g, void* l) {
  __builtin_amdgcn_global_load_lds((const AS1 unsigned int*)g, (AS3 unsigned int*)l, 16, 0, 0);
}

// Coherent-point 16B load with immediate offset (R2-proven sc0|sc1 semantics).
#define LDA1(dst, base, OFF)                                                     \
  asm volatile("global_load_dwordx4 %0, %1, off offset:%c2 sc0 sc1"              \
               : "=v"(dst) : "v"(base), "i"(OFF) : "memory")
#define LDA8(BUF, G)                                                             \
  LDA1(BUF[0], pa, (G) * 256 + 0);   LDA1(BUF[1], pa, (G) * 256 + 32);           \
  LDA1(BUF[2], pa, (G) * 256 + 64);  LDA1(BUF[3], pa, (G) * 256 + 96);           \
  LDA1(BUF[4], pa, (G) * 256 + 128); LDA1(BUF[5], pa, (G) * 256 + 160);          \
  LDA1(BUF[6], pa, (G) * 256 + 192); LDA1(BUF[7], pa, (G) * 256 + 224)
#define MM8(BUF, G)                                                              \
  _Pragma("unroll") for (int i_ = 0; i_ < 8; ++i_)                               \
      ac[i_ & 3] = __builtin_amdgcn_mfma_f32_32x32x16_bf16(                      \
          BUF[i_], bU[(G) * 8 + i_], ac[i_ & 3], 0, 0, 0)

// permuted gate column: packed p = g*64+q, q = gate*16 + j_local  ->  orig col
static __device__ __forceinline__ unsigned orig_col(unsigned p) {
  return ((p & 63u) >> 4) * 512u + (p >> 6) * 16u + (p & 15u);
}

// ---------------- prep: pack weights to bf16 (permuted), biases, h0, flags ----------------
__global__ void prep_kernel(const float* __restrict__ Wx, const float* __restrict__ Uh,
                            const float* __restrict__ bih, const float* __restrict__ bhh,
                            const float* __restrict__ Wy, const float* __restrict__ h0,
                            char* __restrict__ ws) {
  unsigned idx0 = blockIdx.x * blockDim.x + threadIdx.x;
  unsigned stride = gridDim.x * blockDim.x;
  unsigned short* Up = (unsigned short*)(ws + U_OFF);     // [p][k]
  for (unsigned i = idx0; i < 1048576u; i += stride) {
    unsigned k = i & 511u, p = i >> 9;
    Up[i] = f2bf(Uh[k * 2048u + orig_col(p)]);
  }
  unsigned short* Wxp = (unsigned short*)(ws + WX_OFF);   // [p][k]
  for (unsigned i = idx0; i < 524288u; i += stride) {
    unsigned k = i & 255u, p = i >> 8;
    Wxp[i] = f2bf(Wx[k * 2048u + orig_col(p)]);
  }
  unsigned short* Wyp = (unsigned short*)(ws + WY_OFF);   // [n][k]
  for (unsigned i = idx0; i < 131072u; i += stride) {
    unsigned k = i & 511u, n = i >> 9;
    Wyp[i] = f2bf(Wy[k * 256u + n]);
  }
  float* bp = (float*)(ws + BI_OFF);
  for (unsigned p = idx0; p < 2048u; p += stride) {
    unsigned c = orig_col(p);
    bp[p] = bih[c] + bhh[c];
  }
  unsigned short* hb = (unsigned short*)(ws + HB_OFF);
  for (unsigned i = idx0; i < 32768u; i += stride) hb[i] = f2bf(h0[i]);
  for (unsigned i = idx0; i < 512u; i += stride)
    ((unsigned*)(ws + FL_OFF))[i] = 0u;
}

// ---------------- xproj: xp[t][g][b][q] (bf16) = x @ WxT + bias ----------------
__launch_bounds__(256, 1)
__global__ void xproj_kernel(const float* __restrict__ x, char* __restrict__ ws) {
  extern __shared__ char smem[];
  char* a_lds = smem;            // [128 r][256 k] bf16 swizzled (64KB)
  char* b_lds = smem + 65536;    // [128 p][256 k] bf16 swizzled (64KB)
  const int tid = threadIdx.x, lane = tid & 63, wid = tid >> 6;
  const int wm = wid >> 1, wn = wid & 1;
  const int r0 = blockIdx.x * 128, p0 = blockIdx.y * 128;
  const unsigned short* WxT = (const unsigned short*)(ws + WX_OFF);

#pragma unroll
  for (int i = 0; i < 16; ++i) {
    int base = i * 4096 + wid * 1024;
    int byte = base + lane * 16;
    int row = byte >> 9;
    int kb = (byte >> 4) & 31;
    gld_lds16(WxT + (size_t)(p0 + row) * 256 + (size_t)((kb ^ (row & 15)) * 8), b_lds + base);
  }
  {
    int row = tid >> 1, half = tid & 1;
    const float* xr = x + (size_t)(r0 + row) * 256 + half * 128;
    char* ar = a_lds + row * 512;
#pragma unroll
    for (int i = 0; i < 16; ++i) {
      float4 f0 = *(const float4*)(xr + i * 8);
      float4 f1 = *(const float4*)(xr + i * 8 + 4);
      short8 v;
      v[0] = (short)f2bf(f0.x); v[1] = (short)f2bf(f0.y); v[2] = (short)f2bf(f0.z); v[3] = (short)f2bf(f0.w);
      v[4] = (short)f2bf(f1.x); v[5] = (short)f2bf(f1.y); v[6] = (short)f2bf(f1.z); v[7] = (short)f2bf(f1.w);
      int kb = half * 16 + i;
      *(short8*)(ar + ((kb ^ (row & 15)) * 16)) = v;
    }
  }
  __syncthreads();

  f32x16 acc[2][2] = {};
#pragma unroll
  for (int kk = 0; kk < 16; ++kk) {
    int kbW = kk * 2 + (lane >> 5);
    short8 a[2], b[2];
#pragma unroll
    for (int mt = 0; mt < 2; ++mt) {
      int row = wm * 64 + mt * 32 + (lane & 31);
      a[mt] = *(const short8*)(a_lds + row * 512 + ((kbW ^ (row & 15)) * 16));
    }
#pragma unroll
    for (int nt = 0; nt < 2; ++nt) {
      int n = wn * 64 + nt * 32 + (lane & 31);
      b[nt] = *(const short8*)(b_lds + n * 512 + ((kbW ^ (n & 15)) * 16));
    }
#pragma unroll
    for (int mt = 0; mt < 2; ++mt)
#pragma unroll
      for (int nt = 0; nt < 2; ++nt)
        acc[mt][nt] = __builtin_amdgcn_mfma_f32_32x32x16_bf16(a[mt], b[nt], acc[mt][nt], 0, 0, 0);
  }

  const float* bias = (const float*)(ws + BI_OFF);
  unsigned short* xp = (unsigned short*)(ws + XP_OFF);
#pragma unroll
  for (int nt = 0; nt < 2; ++nt) {
    int p = p0 + wn * 64 + nt * 32 + (lane & 31);
    float bv = bias[p];
    int g = p >> 6, q = p & 63;
#pragma unroll
    for (int mt = 0; mt < 2; ++mt) {
#pragma unroll
      for (int rg = 0; rg < 16; ++rg) {
        int r = r0 + wm * 64 + mt * 32 + (rg & 3) + 8 * (rg >> 2) + 4 * (lane >> 5);
        int b = r >> 9, t = r & 511;
        xp[((size_t)(t * 32 + g) * 64 + b) * 64 + q] = f2bf(acc[mt][nt][rg] + bv);
      }
    }
  }
}

// ---------------- persistent recurrent kernel: 32 wgs, one per 64-gate-col slice ----------------
// Coherence protocol identical to proven R2 (agent atomics + sc0 sc1 loads).
// New vs R2: (a) 32 distributed flags instead of one counter; (b) h[t] streamed
// global->VGPR (sc0 sc1, counted vmcnt groups) instead of global_load_lds + ds_read.
__launch_bounds__(256, 1)
__global__ void lstm_rec_kernel(const float* __restrict__ c0, char* __restrict__ ws,
                                float* __restrict__ out) {
  __shared__ float gates[64 * 68];
  const int tid = threadIdx.x, lane = tid & 63, wid = tid >> 6;
  const int wm = wid >> 1, wn = wid & 1;
  const int g = blockIdx.x;
  char* hbuf = ws + HB_OFF;
  const unsigned short* xp = (const unsigned short*)(ws + XP_OFF);
  unsigned short* hs = (unsigned short*)(ws + HS_OFF);
  unsigned* flags = (unsigned*)(ws + FL_OFF);
  unsigned* myflag = flags + (size_t)g * 16;
  unsigned* pollp = flags + (size_t)(lane & 31) * 16;

  // U_h slice -> 128 VGPRs, held for all 512 steps. Wave wn owns cols [wn*32, wn*32+32).
  const unsigned short* Up = (const unsigned short*)(ws + U_OFF) + (size_t)g * 64 * 512;
  short8 bU[32];
  {
    int n = wn * 32 + (lane & 31);
    int ko = (lane >> 5) * 8;
#pragma unroll
    for (int kk = 0; kk < 32; ++kk)
      bU[kk] = *(const short8*)(Up + (size_t)n * 512 + kk * 16 + ko);
  }
  // elementwise ownership: thread -> (b=eb, j = g*16 + j0 .. +4); c lives in regs
  const int eb = tid >> 2, jg = tid & 3, j0 = jg * 4;
  float4 c = *(const float4*)(c0 + (size_t)eb * 512 + g * 16 + j0);
  // A-fragment base: row = wm*32 + (lane&31), k-offset (lane>>5)*8 elems
  const char* paBase = hbuf + (size_t)(wm * 32 + (lane & 31)) * 1024 + (lane >> 5) * 16;

  for (int t = 0; t < 512; ++t) {
    // xp chunk -> regs (independent of h; latency hides under the poll)
    const unsigned short* xptg = xp + (size_t)(t * 32 + g) * 4096 + eb * 64 + j0;
    ushort4 xq0 = *(const ushort4*)(xptg);
    ushort4 xq1 = *(const ushort4*)(xptg + 16);
    ushort4 xq2 = *(const ushort4*)(xptg + 32);
    ushort4 xq3 = *(const ushort4*)(xptg + 48);
    // wait: every producer's flag >= t (one flag per lane, 32 lines)
    {
      unsigned tgt = (unsigned)t;
      while (__any(__hip_atomic_load(pollp, __ATOMIC_RELAXED, __HIP_MEMORY_SCOPE_AGENT) < tgt)) {}
    }
    // clean vmem counter so the counted vmcnt(8) groups below are exact
    asm volatile("s_waitcnt vmcnt(0)" ::: "memory");
    __builtin_amdgcn_sched_barrier(0);

    // gates GEMM: [64,512] x [512,64]; A streamed from coherent point to VGPRs
    const char* pa = paBase + (t & 1) * 65536;
    short8 Aa[8], Ab[8];
    f32x16 ac[4] = {};
    LDA8(Aa, 0);
    LDA8(Ab, 1);
    asm volatile("s_waitcnt vmcnt(8)" ::: "memory");
    __builtin_amdgcn_sched_barrier(0);
    MM8(Aa, 0);
    LDA8(Aa, 2);
    asm volatile("s_waitcnt vmcnt(8)" ::: "memory");
    __builtin_amdgcn_sched_barrier(0);
    MM8(Ab, 1);
    LDA8(Ab, 3);
    asm volatile("s_waitcnt vmcnt(8)" ::: "memory");
    __builtin_amdgcn_sched_barrier(0);
    MM8(Aa, 2);
    asm volatile("s_waitcnt vmcnt(0)" ::: "memory");
    __builtin_amdgcn_sched_barrier(0);
    MM8(Ab, 3);
    f32x16 acc = (ac[0] + ac[1]) + (ac[2] + ac[3]);
    {
      int q = wn * 32 + (lane & 31);
      int rb = wm * 32 + 4 * (lane >> 5);
#pragma unroll
      for (int rg = 0; rg < 16; ++rg)
        gates[(rb + (rg & 3) + 8 * (rg >> 2)) * 68 + q] = acc[rg];
    }
    __syncthreads();

    // elementwise LSTM cell
    float4 gI = *(const float4*)(gates + eb * 68 + j0);
    float4 gF = *(const float4*)(gates + eb * 68 + 16 + j0);
    float4 gJ = *(const float4*)(gates + eb * 68 + 32 + j0);
    float4 gO = *(const float4*)(gates + eb * 68 + 48 + j0);
    float gi[4] = {gI.x, gI.y, gI.z, gI.w};
    float gf[4] = {gF.x, gF.y, gF.z, gF.w};
    float gj[4] = {gJ.x, gJ.y, gJ.z, gJ.w};
    float go[4] = {gO.x, gO.y, gO.z, gO.w};
    float xi[4] = {bf2f(xq0.x), bf2f(xq0.y), bf2f(xq0.z), bf2f(xq0.w)};
    float xf[4] = {bf2f(xq1.x), bf2f(xq1.y), bf2f(xq1.z), bf2f(xq1.w)};
    float xj[4] = {bf2f(xq2.x), bf2f(xq2.y), bf2f(xq2.z), bf2f(xq2.w)};
    float xo[4] = {bf2f(xq3.x), bf2f(xq3.y), bf2f(xq3.z), bf2f(xq3.w)};
    float cc[4] = {c.x, c.y, c.z, c.w};
    float hh[4];
#pragma unroll
    for (int e = 0; e < 4; ++e) {
      float iv = sigf(gi[e] + xi[e]);
      float fv = sigf(gf[e] + xf[e]);
      float jv = tanhf_(gj[e] + xj[e]);
      float ov = sigf(go[e] + xo[e]);
      float cn = fv * cc[e] + iv * jv;
      cc[e] = cn;
      hh[e] = ov * tanhf_(cn);
    }
    c = make_float4(cc[0], cc[1], cc[2], cc[3]);

    ushort4 hv = make_ushort4(f2bf(hh[0]), f2bf(hh[1]), f2bf(hh[2]), f2bf(hh[3]));
    // coherent store of next-step h (R2-proven agent atomic u64)
    union { ushort4 u4; unsigned long long u64; } hcvt;
    hcvt.u4 = hv;
    __hip_atomic_store((unsigned long long*)(hbuf + ((t + 1) & 1) * 65536 +
                                             (size_t)(eb * 512 + g * 16 + j0) * 2),
                       hcvt.u64, __ATOMIC_RELAXED, __HIP_MEMORY_SCOPE_AGENT);
    // drain h stores, then publish flag
    asm volatile("s_waitcnt vmcnt(0)" ::: "memory");
    __syncthreads();
    if (tid == 0)
      __hip_atomic_store(myflag, (unsigned)(t + 1), __ATOMIC_RELAXED, __HIP_MEMORY_SCOPE_AGENT);
    // fire-and-forget outputs (off the critical path)
    *(ushort4*)(hs + (size_t)(eb * 512 + t) * 512 + g * 16 + j0) = hv;
    if (t == 511) {
      *(float4*)(out + 8388608u + (size_t)eb * 512 + g * 16 + j0) = make_float4(hh[0], hh[1], hh[2], hh[3]);
      *(float4*)(out + 8421376u + (size_t)eb * 512 + g * 16 + j0) = c;
    }
  }
}

// ---------------- ygemm: out[r][o] = hs @ WyT + b_y ----------------
__launch_bounds__(256, 1)
__global__ void ygemm_kernel(const char* __restrict__ ws, const float* __restrict__ by,
                             float* __restrict__ out) {
  extern __shared__ char smem[];
  char* a_lds = smem;            // [128][128] bf16 swizzled (32KB)
  char* b_lds = smem + 32768;    // [128][128] bf16 swizzled (32KB)
  const int tid = threadIdx.x, lane = tid & 63, wid = tid >> 6;
  const int wm = wid >> 1, wn = wid & 1;
  const int r0 = blockIdx.x * 128, n0 = blockIdx.y * 128;
  const unsigned short* hs = (const unsigned short*)(ws + HS_OFF);
  const unsigned short* WyT = (const unsigned short*)(ws + WY_OFF);

  f32x16 acc[2][2] = {};
  for (int k0 = 0; k0 < 512; k0 += 128) {
#pragma unroll
    for (int i = 0; i < 8; ++i) {
      int base = i * 4096 + wid * 1024;
      int byte = base + lane * 16;
      int row = byte >> 8;
      int kb = (byte >> 4) & 15;
      gld_lds16(hs + (size_t)(r0 + row) * 512 + k0 + ((kb ^ (row & 15)) * 8), a_lds + base);
      gld_lds16(WyT + (size_t)(n0 + row) * 512 + k0 + ((kb ^ (row & 15)) * 8), b_lds + base);
    }
    __syncthreads();
#pragma unroll
    for (int kk = 0; kk < 8; ++kk) {
      int kbW = kk * 2 + (lane >> 5);
      short8 a[2], b[2];
#pragma unroll
      for (int mt = 0; mt < 2; ++mt) {
        int row = wm * 64 + mt * 32 + (lane & 31);
        a[mt] = *(const short8*)(a_lds + row * 256 + ((kbW ^ (row & 15)) * 16));
        int n = wn * 64 + mt * 32 + (lane & 31);
        b[mt] = *(const short8*)(b_lds + n * 256 + ((kbW ^ (n & 15)) * 16));
      }
#pragma unroll
      for (int mt = 0; mt < 2; ++mt)
#pragma unroll
        for (int nt = 0; nt < 2; ++nt)
          acc[mt][nt] = __builtin_amdgcn_mfma_f32_32x32x16_bf16(a[mt], b[nt], acc[mt][nt], 0, 0, 0);
    }
    __syncthreads();
  }
#pragma unroll
  for (int nt = 0; nt < 2; ++nt) {
    int o = n0 + wn * 64 + nt * 32 + (lane & 31);
    float bv = by[o];
#pragma unroll
    for (int mt = 0; mt < 2; ++mt)
#pragma unroll
      for (int rg = 0; rg < 16; ++rg) {
        int r = r0 + wm * 64 + mt * 32 + (rg & 3) + 8 * (rg >> 2) + 4 * (lane >> 5);
        out[(size_t)r * 256 + o] = acc[mt][nt][rg] + bv;
      }
  }
}

extern "C" void kernel_launch(void* const* d_in, const int* in_sizes, int n_in,
                              void* d_out, int out_size, void* d_ws, size_t ws_size,
                              hipStream_t stream) {
  (void)in_sizes; (void)n_in; (void)out_size; (void)ws_size;
  const float* x   = (const float*)d_in[0];
  const float* h0  = (const float*)d_in[1];
  const float* c0  = (const float*)d_in[2];
  const float* Wx  = (const float*)d_in[3];
  const float* Uh  = (const float*)d_in[4];
  const float* bih = (const float*)d_in[5];
  const float* bhh = (const float*)d_in[6];
  const float* Wy  = (const float*)d_in[7];
  const float* by  = (const float*)d_in[8];
  char* ws = (char*)d_ws;
  float* out = (float*)d_out;

  prep_kernel<<<1024, 256, 0, stream>>>(Wx, Uh, bih, bhh, Wy, h0, ws);
  xproj_kernel<<<dim3(256, 16), 256, 131072, stream>>>(x, ws);
  lstm_rec_kernel<<<32, 256, 0, stream>>>(c0, ws, out);
  ygemm_kernel<<<dim3(256, 2), 256, 65536, stream>>>(ws, by, out);
}

// Round 6
// 2280.592 us; speedup vs baseline: 1.5150x; 1.5150x over previous
//
#include <hip/hip_runtime.h>

typedef short short8 __attribute__((ext_vector_type(8)));
typedef float f32x16 __attribute__((ext_vector_type(16)));

#define AS1 __attribute__((address_space(1)))
#define AS3 __attribute__((address_space(3)))

// ---- workspace layout (bytes) ----
static constexpr size_t XP_OFF = 0;            // xp bf16 [T=512][G=32][B=64][Q=64]  134217728
static constexpr size_t HS_OFF = 134217728;    // hs bf16 [B*T=32768][H=512]          33554432
static constexpr size_t U_OFF  = 167772160;    // U  bf16 [P=2048][K=512]              2097152
static constexpr size_t WX_OFF = 169869312;    // WxT bf16 [P=2048][K=256]             1048576
static constexpr size_t WY_OFF = 170917888;    // WyT bf16 [N=256][K=512]               262144
static constexpr size_t BI_OFF = 171180032;    // bias fp32 [2048] (permuted)             8192
static constexpr size_t HB_OFF = 171188224;    // h ping-pong bf16 2 x [64][512]         131072
static constexpr size_t FL_OFF = 171319296;    // flags [32] x 64B                        2048

static __device__ __forceinline__ unsigned short f2bf(float f) {
  unsigned u = __float_as_uint(f);
  unsigned r = (u + 0x7fffu + ((u >> 16) & 1u)) >> 16;
  return (unsigned short)r;
}
static __device__ __forceinline__ float bf2f(unsigned short s) {
  return __uint_as_float(((unsigned)s) << 16);
}
static __device__ __forceinline__ float sigf(float x) { return 1.0f / (1.0f + __expf(-x)); }
static __device__ __forceinline__ float tanhf_(float x) { return 1.0f - 2.0f / (1.0f + __expf(2.0f * x)); }

static __device__ __forceinline__ void gld_lds16(const void* g, void* l) {
  __builtin_amdgcn_global_load_lds((const AS1 unsigned int*)g, (AS3 unsigned int*)l, 16, 0, 0);
}
// coherent variant (R2-proven): aux = sc0|sc1 -> bypass L1/L2, read at the agent-coherent point
static __device__ __forceinline__ void gld_lds16_sc(const void* g, void* l) {
  __builtin_amdgcn_global_load_lds((const AS1 unsigned int*)g, (AS3 unsigned int*)l, 16, 0, 17);
}

#define DO32(M) M(0) M(1) M(2) M(3) M(4) M(5) M(6) M(7) M(8) M(9) M(10) M(11) \
  M(12) M(13) M(14) M(15) M(16) M(17) M(18) M(19) M(20) M(21) M(22) M(23)     \
  M(24) M(25) M(26) M(27) M(28) M(29) M(30) M(31)

// permuted gate column: packed p = g*64+q, q = gate*16 + j_local  ->  orig col
static __device__ __forceinline__ unsigned orig_col(unsigned p) {
  return ((p & 63u) >> 4) * 512u + (p >> 6) * 16u + (p & 15u);
}

// ---------------- prep: pack weights to bf16 (permuted), biases, h0, flags ----------------
__global__ void prep_kernel(const float* __restrict__ Wx, const float* __restrict__ Uh,
                            const float* __restrict__ bih, const float* __restrict__ bhh,
                            const float* __restrict__ Wy, const float* __restrict__ h0,
                            char* __restrict__ ws) {
  unsigned idx0 = blockIdx.x * blockDim.x + threadIdx.x;
  unsigned stride = gridDim.x * blockDim.x;
  unsigned short* Up = (unsigned short*)(ws + U_OFF);     // [p][k]
  for (unsigned i = idx0; i < 1048576u; i += stride) {
    unsigned k = i & 511u, p = i >> 9;
    Up[i] = f2bf(Uh[k * 2048u + orig_col(p)]);
  }
  unsigned short* Wxp = (unsigned short*)(ws + WX_OFF);   // [p][k]
  for (unsigned i = idx0; i < 524288u; i += stride) {
    unsigned k = i & 255u, p = i >> 8;
    Wxp[i] = f2bf(Wx[k * 2048u + orig_col(p)]);
  }
  unsigned short* Wyp = (unsigned short*)(ws + WY_OFF);   // [n][k]
  for (unsigned i = idx0; i < 131072u; i += stride) {
    unsigned k = i & 511u, n = i >> 9;
    Wyp[i] = f2bf(Wy[k * 256u + n]);
  }
  float* bp = (float*)(ws + BI_OFF);
  for (unsigned p = idx0; p < 2048u; p += stride) {
    unsigned c = orig_col(p);
    bp[p] = bih[c] + bhh[c];
  }
  unsigned short* hb = (unsigned short*)(ws + HB_OFF);
  for (unsigned i = idx0; i < 32768u; i += stride) hb[i] = f2bf(h0[i]);
  for (unsigned i = idx0; i < 512u; i += stride)
    ((unsigned*)(ws + FL_OFF))[i] = 0u;
}

// ---------------- xproj: xp[t][g][b][q] (bf16) = x @ WxT + bias ----------------
__launch_bounds__(256, 1)
__global__ void xproj_kernel(const float* __restrict__ x, char* __restrict__ ws) {
  extern __shared__ char smem[];
  char* a_lds = smem;            // [128 r][256 k] bf16 swizzled (64KB)
  char* b_lds = smem + 65536;    // [128 p][256 k] bf16 swizzled (64KB)
  const int tid = threadIdx.x, lane = tid & 63, wid = tid >> 6;
  const int wm = wid >> 1, wn = wid & 1;
  const int r0 = blockIdx.x * 128, p0 = blockIdx.y * 128;
  const unsigned short* WxT = (const unsigned short*)(ws + WX_OFF);

#pragma unroll
  for (int i = 0; i < 16; ++i) {
    int base = i * 4096 + wid * 1024;
    int byte = base + lane * 16;
    int row = byte >> 9;
    int kb = (byte >> 4) & 31;
    gld_lds16(WxT + (size_t)(p0 + row) * 256 + (size_t)((kb ^ (row & 15)) * 8), b_lds + base);
  }
  {
    int row = tid >> 1, half = tid & 1;
    const float* xr = x + (size_t)(r0 + row) * 256 + half * 128;
    char* ar = a_lds + row * 512;
#pragma unroll
    for (int i = 0; i < 16; ++i) {
      float4 f0 = *(const float4*)(xr + i * 8);
      float4 f1 = *(const float4*)(xr + i * 8 + 4);
      short8 v;
      v[0] = (short)f2bf(f0.x); v[1] = (short)f2bf(f0.y); v[2] = (short)f2bf(f0.z); v[3] = (short)f2bf(f0.w);
      v[4] = (short)f2bf(f1.x); v[5] = (short)f2bf(f1.y); v[6] = (short)f2bf(f1.z); v[7] = (short)f2bf(f1.w);
      int kb = half * 16 + i;
      *(short8*)(ar + ((kb ^ (row & 15)) * 16)) = v;
    }
  }
  __syncthreads();

  f32x16 acc[2][2] = {};
#pragma unroll
  for (int kk = 0; kk < 16; ++kk) {
    int kbW = kk * 2 + (lane >> 5);
    short8 a[2], b[2];
#pragma unroll
    for (int mt = 0; mt < 2; ++mt) {
      int row = wm * 64 + mt * 32 + (lane & 31);
      a[mt] = *(const short8*)(a_lds + row * 512 + ((kbW ^ (row & 15)) * 16));
    }
#pragma unroll
    for (int nt = 0; nt < 2; ++nt) {
      int n = wn * 64 + nt * 32 + (lane & 31);
      b[nt] = *(const short8*)(b_lds + n * 512 + ((kbW ^ (n & 15)) * 16));
    }
#pragma unroll
    for (int mt = 0; mt < 2; ++mt)
#pragma unroll
      for (int nt = 0; nt < 2; ++nt)
        acc[mt][nt] = __builtin_amdgcn_mfma_f32_32x32x16_bf16(a[mt], b[nt], acc[mt][nt], 0, 0, 0);
  }

  const float* bias = (const float*)(ws + BI_OFF);
  unsigned short* xp = (unsigned short*)(ws + XP_OFF);
#pragma unroll
  for (int nt = 0; nt < 2; ++nt) {
    int p = p0 + wn * 64 + nt * 32 + (lane & 31);
    float bv = bias[p];
    int g = p >> 6, q = p & 63;
#pragma unroll
    for (int mt = 0; mt < 2; ++mt) {
#pragma unroll
      for (int rg = 0; rg < 16; ++rg) {
        int r = r0 + wm * 64 + mt * 32 + (rg & 3) + 8 * (rg >> 2) + 4 * (lane >> 5);
        int b = r >> 9, t = r & 511;
        xp[((size_t)(t * 32 + g) * 64 + b) * 64 + q] = f2bf(acc[mt][nt][rg] + bv);
      }
    }
  }
}

// ---------------- persistent recurrent kernel: 32 wgs, one per 64-gate-col slice ----------------
// Protocol = R2-proven: agent atomic h stores, sc0|sc1 coherent staging loads,
// per-wave vmcnt(0) drain -> __syncthreads -> publish. Changes vs R2:
//  (a) single RMW counter -> 32 per-wg flags (64B-separated), store-publish,
//      wave-0-only wave-parallel poll (one RT per poll iteration, no RMW queue);
//  (b) bU pinned in 128 VGPRs via prologue asm volatile loads (low-pressure
//      window -> no spill before the waitcnt; volatile -> no rematerialization).
__launch_bounds__(256, 1)
__global__ void lstm_rec_kernel(const float* __restrict__ c0, char* __restrict__ ws,
                                float* __restrict__ out) {
  extern __shared__ char smem[];
  char* h_lds = smem;                        // [64][512] bf16 swizzled (64KB)
  float* gates = (float*)(smem + 65536);     // [64][68] fp32
  const int tid = threadIdx.x, lane = tid & 63, wid = tid >> 6;
  const int wm = wid >> 1, wn = wid & 1;
  const int g = blockIdx.x;
  char* hbuf = ws + HB_OFF;
  const unsigned short* xp = (const unsigned short*)(ws + XP_OFF);
  unsigned short* hs = (unsigned short*)(ws + HS_OFF);
  unsigned* flags = (unsigned*)(ws + FL_OFF);
  unsigned* myflag = flags + (size_t)g * 16;
  unsigned* pollp = flags + (size_t)(lane & 31) * 16;

  // U_h slice -> 128 VGPRs, pinned once at the prologue.
  short8 bU[32];
  {
    const unsigned short* Up = (const unsigned short*)(ws + U_OFF) + (size_t)g * 64 * 512;
    const unsigned short* pu = Up + (size_t)(wn * 32 + (lane & 31)) * 512 + (lane >> 5) * 8;
#define LDU(k) asm volatile("global_load_dwordx4 %0, %1, off offset:%c2" \
                            : "=v"(bU[k]) : "v"(pu), "i"((k) * 32) : "memory");
    DO32(LDU)
#undef LDU
    asm volatile("s_waitcnt vmcnt(0)" ::: "memory");
    __builtin_amdgcn_sched_barrier(0);
  }
  // elementwise ownership: thread -> (b=eb, j = g*16 + j0 .. +4); c lives in regs
  const int eb = tid >> 2, jg = tid & 3, j0 = jg * 4;
  float4 c = *(const float4*)(c0 + (size_t)eb * 512 + g * 16 + j0);

  for (int t = 0; t < 512; ++t) {
    // xp chunk -> regs (independent of h; overlaps the poll/staging)
    const unsigned short* xptg = xp + (size_t)(t * 32 + g) * 4096 + eb * 64 + j0;
    ushort4 xq0 = *(const ushort4*)(xptg);
    ushort4 xq1 = *(const ushort4*)(xptg + 16);
    ushort4 xq2 = *(const ushort4*)(xptg + 32);
    ushort4 xq3 = *(const ushort4*)(xptg + 48);

    // wait: every producer's flag >= t (wave 0 only; 2 lanes per flag line)
    if (wid == 0) {
      unsigned tgt = (unsigned)t;
      while (__any(__hip_atomic_load(pollp, __ATOMIC_RELAXED, __HIP_MEMORY_SCOPE_AGENT) < tgt)) {}
    }
    __syncthreads();

    // stage h[t] into LDS (coherent reads, pre-swizzled source)
    const char* hb = hbuf + (t & 1) * 65536;
#pragma unroll
    for (int i = 0; i < 16; ++i) {
      int row = i * 4 + wid;
      gld_lds16_sc(hb + row * 1024 + ((lane ^ (row & 15)) * 16), h_lds + i * 4096 + wid * 1024);
    }
    __syncthreads();

    // gates-chunk GEMM: [64,512] x [512,64] — 4 independent accumulator chains
    f32x16 ac[4] = {};
#pragma unroll
    for (int kk = 0; kk < 32; ++kk) {
      int row = wm * 32 + (lane & 31);
      int kbW = kk * 2 + (lane >> 5);
      short8 a = *(const short8*)(h_lds + row * 1024 + ((kbW ^ (row & 15)) * 16));
      ac[kk & 3] = __builtin_amdgcn_mfma_f32_32x32x16_bf16(a, bU[kk], ac[kk & 3], 0, 0, 0);
    }
    f32x16 acc = (ac[0] + ac[1]) + (ac[2] + ac[3]);
    {
      int q = wn * 32 + (lane & 31);
      int rb = wm * 32 + 4 * (lane >> 5);
#pragma unroll
      for (int rg = 0; rg < 16; ++rg)
        gates[(rb + (rg & 3) + 8 * (rg >> 2)) * 68 + q] = acc[rg];
    }
    __syncthreads();

    // elementwise LSTM cell
    float4 gI = *(const float4*)(gates + eb * 68 + j0);
    float4 gF = *(const float4*)(gates + eb * 68 + 16 + j0);
    float4 gJ = *(const float4*)(gates + eb * 68 + 32 + j0);
    float4 gO = *(const float4*)(gates + eb * 68 + 48 + j0);
    float gi[4] = {gI.x, gI.y, gI.z, gI.w};
    float gf[4] = {gF.x, gF.y, gF.z, gF.w};
    float gj[4] = {gJ.x, gJ.y, gJ.z, gJ.w};
    float go[4] = {gO.x, gO.y, gO.z, gO.w};
    float xi[4] = {bf2f(xq0.x), bf2f(xq0.y), bf2f(xq0.z), bf2f(xq0.w)};
    float xf[4] = {bf2f(xq1.x), bf2f(xq1.y), bf2f(xq1.z), bf2f(xq1.w)};
    float xj[4] = {bf2f(xq2.x), bf2f(xq2.y), bf2f(xq2.z), bf2f(xq2.w)};
    float xo[4] = {bf2f(xq3.x), bf2f(xq3.y), bf2f(xq3.z), bf2f(xq3.w)};
    float cc[4] = {c.x, c.y, c.z, c.w};
    float hh[4];
#pragma unroll
    for (int e = 0; e < 4; ++e) {
      float iv = sigf(gi[e] + xi[e]);
      float fv = sigf(gf[e] + xf[e]);
      float jv = tanhf_(gj[e] + xj[e]);
      float ov = sigf(go[e] + xo[e]);
      float cn = fv * cc[e] + iv * jv;
      cc[e] = cn;
      hh[e] = ov * tanhf_(cn);
    }
    c = make_float4(cc[0], cc[1], cc[2], cc[3]);

    ushort4 hv = make_ushort4(f2bf(hh[0]), f2bf(hh[1]), f2bf(hh[2]), f2bf(hh[3]));
    // coherent store of next-step h (R2-proven agent atomic u64)
    union { ushort4 u4; unsigned long long u64; } hcvt;
    hcvt.u4 = hv;
    __hip_atomic_store((unsigned long long*)(hbuf + ((t + 1) & 1) * 65536 +
                                             (size_t)(eb * 512 + g * 16 + j0) * 2),
                       hcvt.u64, __ATOMIC_RELAXED, __HIP_MEMORY_SCOPE_AGENT);
    // hs record rides the same drain (not on the critical path)
    *(ushort4*)(hs + (size_t)(eb * 512 + t) * 512 + g * 16 + j0) = hv;
    if (t == 511) {
      *(float4*)(out + 8388608u + (size_t)eb * 512 + g * 16 + j0) = make_float4(hh[0], hh[1], hh[2], hh[3]);
      *(float4*)(out + 8421376u + (size_t)eb * 512 + g * 16 + j0) = c;
    }
    // drain own stores to the coherent point, then publish (store, no RMW)
    asm volatile("s_waitcnt vmcnt(0)" ::: "memory");
    __syncthreads();
    if (tid == 0)
      __hip_atomic_store(myflag, (unsigned)(t + 1), __ATOMIC_RELAXED, __HIP_MEMORY_SCOPE_AGENT);
  }
}

// ---------------- ygemm: out[r][o] = hs @ WyT + b_y ----------------
__launch_bounds__(256, 1)
__global__ void ygemm_kernel(const char* __restrict__ ws, const float* __restrict__ by,
                             float* __restrict__ out) {
  extern __shared__ char smem[];
  char* a_lds = smem;            // [128][128] bf16 swizzled (32KB)
  char* b_lds = smem + 32768;    // [128][128] bf16 swizzled (32KB)
  const int tid = threadIdx.x, lane = tid & 63, wid = tid >> 6;
  const int wm = wid >> 1, wn = wid & 1;
  const int r0 = blockIdx.x * 128, n0 = blockIdx.y * 128;
  const unsigned short* hs = (const unsigned short*)(ws + HS_OFF);
  const unsigned short* WyT = (const unsigned short*)(ws + WY_OFF);

  f32x16 acc[2][2] = {};
  for (int k0 = 0; k0 < 512; k0 += 128) {
#pragma unroll
    for (int i = 0; i < 8; ++i) {
      int base = i * 4096 + wid * 1024;
      int byte = base + lane * 16;
      int row = byte >> 8;
      int kb = (byte >> 4) & 15;
      gld_lds16(hs + (size_t)(r0 + row) * 512 + k0 + ((kb ^ (row & 15)) * 8), a_lds + base);
      gld_lds16(WyT + (size_t)(n0 + row) * 512 + k0 + ((kb ^ (row & 15)) * 8), b_lds + base);
    }
    __syncthreads();
#pragma unroll
    for (int kk = 0; kk < 8; ++kk) {
      int kbW = kk * 2 + (lane >> 5);
      short8 a[2], b[2];
#pragma unroll
      for (int mt = 0; mt < 2; ++mt) {
        int row = wm * 64 + mt * 32 + (lane & 31);
        a[mt] = *(const short8*)(a_lds + row * 256 + ((kbW ^ (row & 15)) * 16));
        int n = wn * 64 + mt * 32 + (lane & 31);
        b[mt] = *(const short8*)(b_lds + n * 256 + ((kbW ^ (n & 15)) * 16));
      }
#pragma unroll
      for (int mt = 0; mt < 2; ++mt)
#pragma unroll
        for (int nt = 0; nt < 2; ++nt)
          acc[mt][nt] = __builtin_amdgcn_mfma_f32_32x32x16_bf16(a[mt], b[nt], acc[mt][nt], 0, 0, 0);
    }
    __syncthreads();
  }
#pragma unroll
  for (int nt = 0; nt < 2; ++nt) {
    int o = n0 + wn * 64 + nt * 32 + (lane & 31);
    float bv = by[o];
#pragma unroll
    for (int mt = 0; mt < 2; ++mt)
#pragma unroll
      for (int rg = 0; rg < 16; ++rg) {
        int r = r0 + wm * 64 + mt * 32 + (rg & 3) + 8 * (rg >> 2) + 4 * (lane >> 5);
        out[(size_t)r * 256 + o] = acc[mt][nt][rg] + bv;
      }
  }
}

extern "C" void kernel_launch(void* const* d_in, const int* in_sizes, int n_in,
                              void* d_out, int out_size, void* d_ws, size_t ws_size,
                              hipStream_t stream) {
  (void)in_sizes; (void)n_in; (void)out_size; (void)ws_size;
  const float* x   = (const float*)d_in[0];
  const float* h0  = (const float*)d_in[1];
  const float* c0  = (const float*)d_in[2];
  const float* Wx  = (const float*)d_in[3];
  const float* Uh  = (const float*)d_in[4];
  const float* bih = (const float*)d_in[5];
  const float* bhh = (const float*)d_in[6];
  const float* Wy  = (const float*)d_in[7];
  const float* by  = (const float*)d_in[8];
  char* ws = (char*)d_ws;
  float* out = (float*)d_out;

  prep_kernel<<<1024, 256, 0, stream>>>(Wx, Uh, bih, bhh, Wy, h0, ws);
  xproj_kernel<<<dim3(256, 16), 256, 131072, stream>>>(x, ws);
  lstm_rec_kernel<<<32, 256, 65536 + 64 * 68 * 4, stream>>>(c0, ws, out);
  ygemm_kernel<<<dim3(256, 2), 256, 65536, stream>>>(ws, by, out);
}